// Round 1
// baseline (4295.564 us; speedup 1.0000x reference)
//
#include <hip/hip_runtime.h>
#include <stdint.h>

typedef unsigned long long u64;
typedef unsigned int u32;
typedef unsigned char u8;

// ---------------------------------------------------------------------------
// EdgePool GNN pipeline.  Shapes fixed by the bench: N=100000, E=800000,
// F=128, H=64, G=8, C=10.  All math f32 (reference is f32; no f32 MFMA on
// CDNA4 so GEMMs run on the vector ALU with weights staged in LDS).
// Greedy edge matching: locally-dominant-edge iterative algorithm (exactly
// equivalent to sequential greedy over the stable (-score, idx) order),
// 32 compacted rounds + an exact single-block sequential tail.
// ---------------------------------------------------------------------------

static __device__ __forceinline__ u32 enc_f32(float f) {
  u32 u = __float_as_uint(f);
  return (u & 0x80000000u) ? ~u : (u | 0x80000000u);
}
static __device__ __forceinline__ float dec_f32(u32 u) {
  u32 b = (u & 0x80000000u) ? (u & 0x7fffffffu) : ~u;
  return __uint_as_float(b);
}

// out[n][64] = in[n][K] @ W[64][K]^T     (W staged in LDS, lane-uniform reads)
template <int K>
__global__ void k_transform(const float* __restrict__ x, const float* __restrict__ w,
                            float* __restrict__ out, int n) {
  __shared__ float ws[64 * K];
  for (int i = threadIdx.x; i < 64 * K; i += blockDim.x) ws[i] = w[i];
  __syncthreads();
  int node = blockIdx.x * blockDim.x + threadIdx.x;
  if (node >= n) return;
  const float* xr = x + (size_t)node * K;
  float acc[64];
#pragma unroll
  for (int o = 0; o < 64; ++o) acc[o] = 0.f;
  for (int k = 0; k < K; k += 4) {
    float4 xv = *reinterpret_cast<const float4*>(xr + k);
#pragma unroll
    for (int o = 0; o < 64; ++o) {
      float4 wv = *reinterpret_cast<const float4*>(&ws[o * K + k]);
      acc[o] = fmaf(xv.x, wv.x, acc[o]);
      acc[o] = fmaf(xv.y, wv.y, acc[o]);
      acc[o] = fmaf(xv.z, wv.z, acc[o]);
      acc[o] = fmaf(xv.w, wv.w, acc[o]);
    }
  }
  float4* orow = reinterpret_cast<float4*>(out + (size_t)node * 64);
#pragma unroll
  for (int o = 0; o < 16; ++o)
    orow[o] = make_float4(acc[4 * o], acc[4 * o + 1], acc[4 * o + 2], acc[4 * o + 3]);
}

__global__ void k_count(const int* __restrict__ dst, int* __restrict__ cnt, int e) {
  int i = blockIdx.x * blockDim.x + threadIdx.x;
  if (i < e) atomicAdd(&cnt[dst[i]], 1);
}

// one wave per edge, lane = feature; skip sentinel src>=nvalid
__global__ void k_aggregate(const float* __restrict__ r, const int* __restrict__ src,
                            const int* __restrict__ dst, float* __restrict__ agg,
                            int e, int nvalid) {
  int idx = blockIdx.x * blockDim.x + threadIdx.x;
  int edge = idx >> 6, lane = idx & 63;
  if (edge >= e) return;
  int s = src[edge];
  if (s >= nvalid) return;
  int d = dst[edge];
  atomicAdd(&agg[(size_t)d * 64 + lane], r[(size_t)s * 64 + lane]);
}

// h = relu(agg/max(cnt,1) + b + xin @ w_root^T)
template <int K>
__global__ void k_finish(const float* __restrict__ xin, const float* __restrict__ agg,
                         const int* __restrict__ cnt, const float* __restrict__ w_root,
                         const float* __restrict__ bias, float* __restrict__ hout, int n) {
  __shared__ float ws[64 * K];
  for (int i = threadIdx.x; i < 64 * K; i += blockDim.x) ws[i] = w_root[i];
  __syncthreads();
  int node = blockIdx.x * blockDim.x + threadIdx.x;
  if (node >= n) return;
  const float* xr = xin + (size_t)node * K;
  float acc[64];
#pragma unroll
  for (int o = 0; o < 64; ++o) acc[o] = bias[o];
  for (int k = 0; k < K; k += 4) {
    float4 xv = *reinterpret_cast<const float4*>(xr + k);
#pragma unroll
    for (int o = 0; o < 64; ++o) {
      float4 wv = *reinterpret_cast<const float4*>(&ws[o * K + k]);
      acc[o] = fmaf(xv.x, wv.x, acc[o]);
      acc[o] = fmaf(xv.y, wv.y, acc[o]);
      acc[o] = fmaf(xv.z, wv.z, acc[o]);
      acc[o] = fmaf(xv.w, wv.w, acc[o]);
    }
  }
  float cf = (float)cnt[node];
  float inv = cf > 0.f ? 1.f / cf : 0.f;
  const float* ar = agg + (size_t)node * 64;
  float4* hr = reinterpret_cast<float4*>(hout + (size_t)node * 64);
#pragma unroll
  for (int o4 = 0; o4 < 16; ++o4) {
    float4 a = reinterpret_cast<const float4*>(ar)[o4];
    float4 v;
    v.x = fmaf(a.x, inv, acc[4 * o4 + 0]); v.x = v.x > 0.f ? v.x : 0.f;
    v.y = fmaf(a.y, inv, acc[4 * o4 + 1]); v.y = v.y > 0.f ? v.y : 0.f;
    v.z = fmaf(a.z, inv, acc[4 * o4 + 2]); v.z = v.z > 0.f ? v.z : 0.f;
    v.w = fmaf(a.w, inv, acc[4 * o4 + 3]); v.w = v.w > 0.f ? v.w : 0.f;
    hr[o4] = v;
  }
}

// global mean pool: 4 nodes/block (wave per node, lane=feature)
__global__ void k_gmp(const float* __restrict__ h, const int* __restrict__ batch,
                      const int* __restrict__ gP, float* __restrict__ xs_sum,
                      float* __restrict__ gcnt, int count_nodes, int n) {
  int G = *gP;
  int lane = threadIdx.x & 63, w = threadIdx.x >> 6;
  int node = blockIdx.x * 4 + w;
  bool valid = (node < n);
  int g = valid ? batch[node] : -1;
  bool use = valid && g >= 0 && g < G && g < 8;
  float v = use ? h[(size_t)node * 64 + lane] : 0.f;
  if (count_nodes && use && lane == 0) atomicAdd(&gcnt[g], 1.f);
  __shared__ int gs[4];
  __shared__ float sdata[256];
  if (lane == 0) gs[w] = use ? g : -1;
  __syncthreads();
  int guni = -1;
  bool uni = true;
#pragma unroll
  for (int i = 0; i < 4; ++i) {
    int gi = gs[i];
    if (gi >= 0) {
      if (guni < 0) guni = gi;
      else if (guni != gi) uni = false;
    }
  }
  if (uni) {
    if (guni < 0) return;
    sdata[threadIdx.x] = v;
    __syncthreads();
    if (threadIdx.x < 128) sdata[threadIdx.x] += sdata[threadIdx.x + 128];
    __syncthreads();
    if (threadIdx.x < 64) {
      float s = sdata[threadIdx.x] + sdata[threadIdx.x + 64];
      atomicAdd(&xs_sum[guni * 64 + threadIdx.x], s);
    }
  } else {
    if (use) atomicAdd(&xs_sum[g * 64 + lane], v);
  }
}

// raw edge score: dot(concat(h[s],h[d]), pool_w) + pool_b   (wave per edge)
__global__ void k_raw(const float* __restrict__ h, const int* __restrict__ src,
                      const int* __restrict__ dst, const float* __restrict__ pw,
                      const float* __restrict__ pbp, float* __restrict__ raw, int e) {
  int idx = blockIdx.x * blockDim.x + threadIdx.x;
  int edge = idx >> 6, lane = idx & 63;
  if (edge >= e) return;
  int s = src[edge], d = dst[edge];
  float v = h[(size_t)s * 64 + lane] * pw[lane] + h[(size_t)d * 64 + lane] * pw[64 + lane];
#pragma unroll
  for (int off = 32; off > 0; off >>= 1) v += __shfl_down(v, off, 64);
  if (lane == 0) raw[edge] = v + pbp[0];
}

__global__ void k_max(const float* __restrict__ raw, const int* __restrict__ dst,
                      u32* __restrict__ m_enc, int e) {
  int i = blockIdx.x * blockDim.x + threadIdx.x;
  if (i < e) atomicMax(&m_enc[dst[i]], enc_f32(raw[i]));
}

__global__ void k_den(const float* __restrict__ raw, const int* __restrict__ dst,
                      const u32* __restrict__ m_enc, float* __restrict__ den, int e) {
  int i = blockIdx.x * blockDim.x + threadIdx.x;
  if (i >= e) return;
  int d = dst[i];
  atomicAdd(&den[d], expf(raw[i] - dec_f32(m_enc[d])));
}

// score (in place over raw), sort key, initial edge list, counters
__global__ void k_score(float* __restrict__ rawsc, const int* __restrict__ dst,
                        const u32* __restrict__ m_enc, const float* __restrict__ den,
                        u64* __restrict__ key, int* __restrict__ listA,
                        int* __restrict__ c0, int e) {
  int i = blockIdx.x * blockDim.x + threadIdx.x;
  if (i == 0) *c0 = e;  // n_in for round 0 (c1, nclus already zeroed)
  if (i >= e) return;
  int d = dst[i];
  float sc = expf(rawsc[i] - dec_f32(m_enc[d])) / den[d] + 0.5f;
  rawsc[i] = sc;
  key[i] = ((u64)(~__float_as_uint(sc)) << 32) | (u32)i;  // score desc, idx asc
  listA[i] = i;
}

// matching round, phase 1: drop dead edges, atomicMin priorities, compact
__global__ void k_mscan(const u64* __restrict__ key, const int* __restrict__ src,
                        const int* __restrict__ dst, const u8* __restrict__ dead,
                        u64* __restrict__ bcur, u64* __restrict__ bnext,
                        const int* __restrict__ list_in, int* __restrict__ list_out,
                        const int* __restrict__ n_in_p, int* __restrict__ n_out_p) {
  int n_in = *n_in_p;
  int stride = gridDim.x * blockDim.x;
  for (int i = blockIdx.x * blockDim.x + threadIdx.x; i < n_in; i += stride) {
    int e = list_in[i];
    int s = src[e], d = dst[e];
    if (dead[s] || dead[d]) continue;
    u64 k = key[e];
    atomicMin(&bcur[s], k);
    if (d != s) atomicMin(&bcur[d], k);
    bnext[s] = ~0ull;  // pre-reset other buffer for next round (benign races)
    bnext[d] = ~0ull;
    int j = atomicAdd(n_out_p, 1);  // compiler wave-aggregates +1 atomics (m20)
    list_out[j] = e;
  }
}

// matching round, phase 2: locally-dominant edges match; zero next counter
__global__ void k_mmatch(const u64* __restrict__ key, const int* __restrict__ src,
                         const int* __restrict__ dst, u8* __restrict__ dead,
                         u8* __restrict__ matched, const u64* __restrict__ bcur,
                         const int* __restrict__ list, const int* __restrict__ n_p,
                         int* __restrict__ zero_me) {
  if (blockIdx.x == 0 && threadIdx.x == 0) *zero_me = 0;
  int n = *n_p;
  int stride = gridDim.x * blockDim.x;
  for (int i = blockIdx.x * blockDim.x + threadIdx.x; i < n; i += stride) {
    int e = list[i];
    int s = src[e], d = dst[e];
    u64 k = key[e];
    if (bcur[s] == k && (d == s || bcur[d] == k)) {
      matched[e] = 1;
      dead[s] = 1;
      dead[d] = 1;
    }
  }
}

// exact sequential tail: repeatedly match the min-key alive edge
__global__ void k_tail(const u64* __restrict__ key, const int* __restrict__ src,
                       const int* __restrict__ dst, u8* dead, u8* matched,
                       const int* __restrict__ list, const int* __restrict__ n_p) {
  __shared__ u64 smk[256];
  __shared__ int sme[256];
  int n = *n_p;
  int tid = threadIdx.x;
  while (true) {
    u64 mk = ~0ull;
    int me = -1;
    for (int i = tid; i < n; i += 256) {
      int e = list[i];
      if (dead[src[e]] || dead[dst[e]]) continue;
      u64 k = key[e];
      if (k < mk) { mk = k; me = e; }
    }
    smk[tid] = mk; sme[tid] = me;
    __syncthreads();
    for (int w = 128; w > 0; w >>= 1) {
      if (tid < w && smk[tid + w] < smk[tid]) { smk[tid] = smk[tid + w]; sme[tid] = sme[tid + w]; }
      __syncthreads();
    }
    if (smk[0] == ~0ull) break;
    if (tid == 0) {
      int e = sme[0];
      matched[e] = 1;
      dead[src[e]] = 1;
      dead[dst[e]] = 1;
      __threadfence_block();
    }
    __syncthreads();
  }
}

__global__ void k_clinit(int* __restrict__ new_batch, const int* __restrict__ gP, int n) {
  int i = blockIdx.x * blockDim.x + threadIdx.x;
  if (i < n) new_batch[i] = *gP;
}

__global__ void k_build_m(const u8* __restrict__ matched, const int* __restrict__ src,
                          const int* __restrict__ dst, const int* __restrict__ batch,
                          int* __restrict__ cluster, int* __restrict__ new_batch,
                          int* __restrict__ nclus, float* __restrict__ gccnt, int e) {
  __shared__ int sc[8];
  if (threadIdx.x < 8) sc[threadIdx.x] = 0;
  __syncthreads();
  int i = blockIdx.x * blockDim.x + threadIdx.x;
  if (i < e && matched[i]) {
    int c = atomicAdd(nclus, 1);
    int s = src[i], d = dst[i];
    cluster[s] = c;
    cluster[d] = c;
    int g = batch[s];
    new_batch[c] = g;
    if (g >= 0 && g < 8) atomicAdd(&sc[g], 1);
  }
  __syncthreads();
  if (threadIdx.x < 8 && sc[threadIdx.x] > 0)
    atomicAdd(&gccnt[threadIdx.x], (float)sc[threadIdx.x]);
}

__global__ void k_build_s(const u8* __restrict__ dead, const int* __restrict__ batch,
                          int* __restrict__ cluster, int* __restrict__ new_batch,
                          int* __restrict__ nclus, float* __restrict__ gccnt, int n) {
  __shared__ int sc[8];
  if (threadIdx.x < 8) sc[threadIdx.x] = 0;
  __syncthreads();
  int i = blockIdx.x * blockDim.x + threadIdx.x;
  if (i < n && !dead[i]) {
    int c = atomicAdd(nclus, 1);
    cluster[i] = c;
    int g = batch[i];
    new_batch[c] = g;
    if (g >= 0 && g < 8) atomicAdd(&sc[g], 1);
  }
  __syncthreads();
  if (threadIdx.x < 8 && sc[threadIdx.x] > 0)
    atomicAdd(&gccnt[threadIdx.x], (float)sc[threadIdx.x]);
}

// new_x rows: matched pairs (scaled by score) and singletons. wave per item.
__global__ void k_newx(const u8* __restrict__ matched, const u8* __restrict__ dead,
                       const int* __restrict__ src, const int* __restrict__ dst,
                       const int* __restrict__ cluster, const float* __restrict__ score,
                       const float* __restrict__ h2, float* __restrict__ new_x,
                       int e, int n) {
  int idx = blockIdx.x * blockDim.x + threadIdx.x;
  int item = idx >> 6, lane = idx & 63;
  if (item < e) {
    if (!matched[item]) return;
    int s = src[item], d = dst[item];
    int c = cluster[s];
    float v = h2[(size_t)s * 64 + lane];
    if (d != s) v += h2[(size_t)d * 64 + lane];
    new_x[(size_t)c * 64 + lane] = v * score[item];
  } else if (item < e + n) {
    int node = item - e;
    if (dead[node]) return;
    new_x[(size_t)cluster[node] * 64 + lane] = h2[(size_t)node * 64 + lane];
  }
}

#define HBITS 21
#define HMASK ((1u << HBITS) - 1u)

// coalesce(cluster[edge_index]): hash-dedup; dups -> sentinel n. counts kept.
__global__ void k_dedup(const int* __restrict__ src, const int* __restrict__ dst,
                        const int* __restrict__ cluster, u64* __restrict__ table,
                        int* __restrict__ ns, int* __restrict__ nd,
                        int* __restrict__ cnt, int e, int n) {
  int i = blockIdx.x * blockDim.x + threadIdx.x;
  if (i >= e) return;
  int cs_ = cluster[src[i]], cd_ = cluster[dst[i]];
  u64 kk = (u64)cs_ * (u64)(n + 1) + (u64)cd_;
  u32 pos = (u32)((kk * 0x9E3779B97F4A7C15ull) >> 43) & HMASK;
  while (true) {
    u64 old = atomicCAS(&table[pos], ~0ull, kk);
    if (old == ~0ull) {
      ns[i] = cs_; nd[i] = cd_;
      atomicAdd(&cnt[cd_], 1);
      return;
    }
    if (old == kk) { ns[i] = n; nd[i] = n; return; }
    pos = (pos + 1) & HMASK;
  }
}

// JumpingKnowledge cat + lin1 + relu + lin2 + log_softmax. single block.
__global__ void k_head(const float* __restrict__ xs_sum /*4*8*64*/,
                       const float* __restrict__ gncnt, const float* __restrict__ gccnt,
                       const float* __restrict__ l1w, const float* __restrict__ l1b,
                       const float* __restrict__ l2w, const float* __restrict__ l2b,
                       const int* __restrict__ gP, float* __restrict__ out, int C) {
  __shared__ float z[8][256];
  __shared__ float z1[8][64];
  __shared__ float z2[8][16];
  int G = *gP;
  int tid = threadIdx.x;
  int p = tid >> 6, f = tid & 63;
  for (int g = 0; g < G; ++g) {
    float c = (p < 2) ? gncnt[g] : gccnt[g];
    if (c < 1.f) c = 1.f;
    z[g][tid] = xs_sum[(p * 8 + g) * 64 + f] / c;
  }
  __syncthreads();
  for (int idx = tid; idx < G * 64; idx += blockDim.x) {
    int g = idx >> 6, o = idx & 63;
    float a = l1b[o];
    for (int k = 0; k < 256; ++k) a = fmaf(z[g][k], l1w[o * 256 + k], a);
    z1[g][o] = a > 0.f ? a : 0.f;
  }
  __syncthreads();
  for (int idx = tid; idx < G * C; idx += blockDim.x) {
    int g = idx / C, c = idx % C;
    float a = l2b[c];
    for (int k = 0; k < 64; ++k) a = fmaf(z1[g][k], l2w[c * 64 + k], a);
    z2[g][c] = a;
  }
  __syncthreads();
  if (tid < G) {
    float m = z2[tid][0];
    for (int c = 1; c < C; ++c) m = fmaxf(m, z2[tid][c]);
    float s = 0.f;
    for (int c = 0; c < C; ++c) s += expf(z2[tid][c] - m);
    float lse = m + logf(s);
    for (int c = 0; c < C; ++c) out[tid * C + c] = z2[tid][c] - lse;
  }
}

extern "C" void kernel_launch(void* const* d_in, const int* in_sizes, int n_in,
                              void* d_out, int out_size, void* d_ws, size_t ws_size,
                              hipStream_t stream) {
  const float* x       = (const float*)d_in[0];
  const int*   ei      = (const int*)d_in[1];
  const int*   batch   = (const int*)d_in[2];
  const float* w_rel1  = (const float*)d_in[3];
  const float* b_rel1  = (const float*)d_in[4];
  const float* w_root1 = (const float*)d_in[5];
  const float* w_rel2  = (const float*)d_in[6];
  const float* b_rel2  = (const float*)d_in[7];
  const float* w_root2 = (const float*)d_in[8];
  const float* w_rel3  = (const float*)d_in[9];
  const float* b_rel3  = (const float*)d_in[10];
  const float* w_root3 = (const float*)d_in[11];
  const float* w_rel4  = (const float*)d_in[12];
  const float* b_rel4  = (const float*)d_in[13];
  const float* w_root4 = (const float*)d_in[14];
  const float* pool_w  = (const float*)d_in[15];
  const float* pool_b  = (const float*)d_in[16];
  const float* lin1_w  = (const float*)d_in[17];
  const float* lin1_b  = (const float*)d_in[18];
  const float* lin2_w  = (const float*)d_in[19];
  const float* lin2_b  = (const float*)d_in[20];
  const int*   gP      = (const int*)d_in[21];
  float* out = (float*)d_out;

  const int N = in_sizes[2];
  const int E = in_sizes[1] / 2;
  const int C = in_sizes[20];
  const int* src = ei;
  const int* dst = ei + E;

  // ---- workspace layout ----
  char* w = (char*)d_ws;
  auto alloc = [&](size_t bytes) -> char* {
    char* p = w;
    w += (bytes + 255) & ~(size_t)255;
    return p;
  };
  float* r      = (float*)alloc((size_t)N * 64 * 4);
  float* agg    = (float*)alloc((size_t)(N + 1) * 64 * 4);  // also hash table region
  float* hA     = (float*)alloc((size_t)N * 64 * 4);        // h1 -> new_x -> h4
  float* hB     = (float*)alloc((size_t)N * 64 * 4);        // h2 -> h3
  float* score  = (float*)alloc((size_t)E * 4);             // raw -> score
  u64*   key    = (u64*)alloc((size_t)E * 8);
  int*   listA  = (int*)alloc((size_t)E * 4);               // later: ns
  int*   listB  = (int*)alloc((size_t)E * 4);               // later: nd
  u64*   best0  = (u64*)alloc((size_t)N * 8);
  u64*   best1  = (u64*)alloc((size_t)N * 8);
  char* zstart = w;                                         // zeroed block
  int*   cnt       = (int*)alloc((size_t)(N + 1) * 4);
  u32*   m_enc     = (u32*)alloc((size_t)N * 4);
  float* den       = (float*)alloc((size_t)N * 4);
  u8*    dead      = (u8*)alloc((size_t)N);
  u8*    matched   = (u8*)alloc((size_t)E);
  int*   cluster   = (int*)alloc((size_t)N * 4);
  int*   new_batch = (int*)alloc((size_t)N * 4);
  float* small     = (float*)alloc(16384);
  size_t zbytes = (size_t)(w - zstart);
  if ((size_t)(w - (char*)d_ws) > ws_size) return;  // fail loudly (output stays poisoned)

  float* xs_sum = small;               // [4][8][64]
  float* gncnt  = small + 2048;        // [8] node counts / graph
  float* gccnt  = small + 2056;        // [8] cluster counts / graph
  int*   cptr   = (int*)(small + 2064);  // c0, c1 (ping-pong list counters)
  int*   nclusP = (int*)(small + 2066);

  const int TB = 256;
  const int gN = (N + TB - 1) / TB;
  const int gE = (E + TB - 1) / TB;
  const int gEw = (int)(((size_t)E * 64 + TB - 1) / TB);
  const int gENw = (int)(((size_t)(E + N) * 64 + TB - 1) / TB);
  const int gGmp = (N + 3) / 4;
  const size_t aggBytes = (size_t)(N + 1) * 64 * 4;

  hipMemsetAsync(zstart, 0, zbytes, stream);
  hipMemsetAsync(best0, 0xFF, (size_t)N * 8, stream);
  hipMemsetAsync(best1, 0xFF, (size_t)N * 8, stream);
  hipMemsetAsync(agg, 0, aggBytes, stream);

  // ---- conv1 (F=128 -> 64) + gmp xs0 ----
  k_transform<128><<<gN, TB, 0, stream>>>(x, w_rel1, r, N);
  k_count<<<gE, TB, 0, stream>>>(dst, cnt, E);
  k_aggregate<<<gEw, TB, 0, stream>>>(r, src, dst, agg, E, N);
  k_finish<128><<<gN, TB, 0, stream>>>(x, agg, cnt, w_root1, b_rel1, hA, N);
  k_gmp<<<gGmp, TB, 0, stream>>>(hA, batch, gP, xs_sum + 0 * 512, gncnt, 1, N);

  // ---- conv2 (64 -> 64) + gmp xs1 ----
  hipMemsetAsync(agg, 0, aggBytes, stream);
  k_transform<64><<<gN, TB, 0, stream>>>(hA, w_rel2, r, N);
  k_aggregate<<<gEw, TB, 0, stream>>>(r, src, dst, agg, E, N);
  k_finish<64><<<gN, TB, 0, stream>>>(hA, agg, cnt, w_root2, b_rel2, hB, N);
  k_gmp<<<gGmp, TB, 0, stream>>>(hB, batch, gP, xs_sum + 1 * 512, nullptr, 0, N);

  // ---- edge pooling: scores ----
  k_raw<<<gEw, TB, 0, stream>>>(hB, src, dst, pool_w, pool_b, score, E);
  k_max<<<gE, TB, 0, stream>>>(score, dst, m_enc, E);
  k_den<<<gE, TB, 0, stream>>>(score, dst, m_enc, den, E);
  k_score<<<gE, TB, 0, stream>>>(score, dst, m_enc, den, key, listA, cptr, E);

  // ---- greedy matching: locally-dominant rounds + exact tail ----
  const int R = 32;
  for (int rr = 0; rr < R; ++rr) {
    u64* bcur = (rr & 1) ? best1 : best0;
    u64* bnext = (rr & 1) ? best0 : best1;
    int* lin = (rr & 1) ? listB : listA;
    int* lout = (rr & 1) ? listA : listB;
    int* cin = cptr + (rr & 1);
    int* cout = cptr + ((rr + 1) & 1);
    k_mscan<<<1024, TB, 0, stream>>>(key, src, dst, dead, bcur, bnext, lin, lout, cin, cout);
    k_mmatch<<<1024, TB, 0, stream>>>(key, src, dst, dead, matched, bcur, lout, cout, cin);
  }
  k_tail<<<1, TB, 0, stream>>>(key, src, dst, dead, matched,
                               (R & 1) ? listB : listA, cptr + (R & 1));

  // ---- clusters, new_x, new_batch ----
  k_clinit<<<gN, TB, 0, stream>>>(new_batch, gP, N);
  k_build_m<<<gE, TB, 0, stream>>>(matched, src, dst, batch, cluster, new_batch, nclusP, gccnt, E);
  k_build_s<<<gN, TB, 0, stream>>>(dead, batch, cluster, new_batch, nclusP, gccnt, N);
  hipMemsetAsync(hA, 0, (size_t)N * 64 * 4, stream);  // hA becomes new_x
  k_newx<<<gENw, TB, 0, stream>>>(matched, dead, src, dst, cluster, score, hB, hA, E, N);

  // ---- coalesce edges (hash in agg region) ----
  hipMemsetAsync(agg, 0xFF, ((size_t)1 << HBITS) * 8, stream);
  hipMemsetAsync(cnt, 0, (size_t)(N + 1) * 4, stream);
  k_dedup<<<gE, TB, 0, stream>>>(src, dst, cluster, (u64*)agg, listA, listB, cnt, E, N);

  // ---- conv3 (64 -> 64) + gmp xs2 ----
  hipMemsetAsync(agg, 0, aggBytes, stream);
  k_transform<64><<<gN, TB, 0, stream>>>(hA, w_rel3, r, N);
  k_aggregate<<<gEw, TB, 0, stream>>>(r, listA, listB, agg, E, N);
  k_finish<64><<<gN, TB, 0, stream>>>(hA, agg, cnt, w_root3, b_rel3, hB, N);
  k_gmp<<<gGmp, TB, 0, stream>>>(hB, new_batch, gP, xs_sum + 2 * 512, nullptr, 0, N);

  // ---- conv4 (64 -> 64) + gmp xs3 ----
  hipMemsetAsync(agg, 0, aggBytes, stream);
  k_transform<64><<<gN, TB, 0, stream>>>(hB, w_rel4, r, N);
  k_aggregate<<<gEw, TB, 0, stream>>>(r, listA, listB, agg, E, N);
  k_finish<64><<<gN, TB, 0, stream>>>(hB, agg, cnt, w_root4, b_rel4, hA, N);
  k_gmp<<<gGmp, TB, 0, stream>>>(hA, new_batch, gP, xs_sum + 3 * 512, nullptr, 0, N);

  // ---- head ----
  k_head<<<1, TB, 0, stream>>>(xs_sum, gncnt, gccnt, lin1_w, lin1_b, lin2_w, lin2_b, gP, out, C);
}

// Round 2
// 2728.082 us; speedup vs baseline: 1.5746x; 1.5746x over previous
//
#include <hip/hip_runtime.h>
#include <stdint.h>

typedef unsigned long long u64;
typedef unsigned int u32;
typedef unsigned char u8;

// ---------------------------------------------------------------------------
// EdgePool GNN pipeline.  Shapes fixed by the bench: N=100000, E=800000,
// F=128, H=64, G=8, C=10.  All math f32 (reference is f32; no f32 MFMA on
// CDNA4 so GEMMs run on the vector ALU with weights staged in LDS).
// Greedy edge matching: locally-dominant-edge iterative algorithm (exactly
// equivalent to sequential greedy over the stable (-score, idx) order),
// 32 compacted rounds + an exact single-block sequential tail.
// R1: k_gmp rewritten as two-stage (LDS ds_add_f32 -> 1 global atomic per
// block per (g,feat)) — R0's version serialized 1.6M global atomics onto
// 512 addresses (4x 1270us dispatches, VALUBusy 0.5%).
// ---------------------------------------------------------------------------

static __device__ __forceinline__ u32 enc_f32(float f) {
  u32 u = __float_as_uint(f);
  return (u & 0x80000000u) ? ~u : (u | 0x80000000u);
}
static __device__ __forceinline__ float dec_f32(u32 u) {
  u32 b = (u & 0x80000000u) ? (u & 0x7fffffffu) : ~u;
  return __uint_as_float(b);
}

// out[n][64] = in[n][K] @ W[64][K]^T     (W staged in LDS, lane-uniform reads)
template <int K>
__global__ void k_transform(const float* __restrict__ x, const float* __restrict__ w,
                            float* __restrict__ out, int n) {
  __shared__ float ws[64 * K];
  for (int i = threadIdx.x; i < 64 * K; i += blockDim.x) ws[i] = w[i];
  __syncthreads();
  int node = blockIdx.x * blockDim.x + threadIdx.x;
  if (node >= n) return;
  const float* xr = x + (size_t)node * K;
  float acc[64];
#pragma unroll
  for (int o = 0; o < 64; ++o) acc[o] = 0.f;
  for (int k = 0; k < K; k += 4) {
    float4 xv = *reinterpret_cast<const float4*>(xr + k);
#pragma unroll
    for (int o = 0; o < 64; ++o) {
      float4 wv = *reinterpret_cast<const float4*>(&ws[o * K + k]);
      acc[o] = fmaf(xv.x, wv.x, acc[o]);
      acc[o] = fmaf(xv.y, wv.y, acc[o]);
      acc[o] = fmaf(xv.z, wv.z, acc[o]);
      acc[o] = fmaf(xv.w, wv.w, acc[o]);
    }
  }
  float4* orow = reinterpret_cast<float4*>(out + (size_t)node * 64);
#pragma unroll
  for (int o = 0; o < 16; ++o)
    orow[o] = make_float4(acc[4 * o], acc[4 * o + 1], acc[4 * o + 2], acc[4 * o + 3]);
}

__global__ void k_count(const int* __restrict__ dst, int* __restrict__ cnt, int e) {
  int i = blockIdx.x * blockDim.x + threadIdx.x;
  if (i < e) atomicAdd(&cnt[dst[i]], 1);
}

// one wave per edge, lane = feature; skip sentinel src>=nvalid
__global__ void k_aggregate(const float* __restrict__ r, const int* __restrict__ src,
                            const int* __restrict__ dst, float* __restrict__ agg,
                            int e, int nvalid) {
  int idx = blockIdx.x * blockDim.x + threadIdx.x;
  int edge = idx >> 6, lane = idx & 63;
  if (edge >= e) return;
  int s = src[edge];
  if (s >= nvalid) return;
  int d = dst[edge];
  atomicAdd(&agg[(size_t)d * 64 + lane], r[(size_t)s * 64 + lane]);
}

// h = relu(agg/max(cnt,1) + b + xin @ w_root^T)
template <int K>
__global__ void k_finish(const float* __restrict__ xin, const float* __restrict__ agg,
                         const int* __restrict__ cnt, const float* __restrict__ w_root,
                         const float* __restrict__ bias, float* __restrict__ hout, int n) {
  __shared__ float ws[64 * K];
  for (int i = threadIdx.x; i < 64 * K; i += blockDim.x) ws[i] = w_root[i];
  __syncthreads();
  int node = blockIdx.x * blockDim.x + threadIdx.x;
  if (node >= n) return;
  const float* xr = xin + (size_t)node * K;
  float acc[64];
#pragma unroll
  for (int o = 0; o < 64; ++o) acc[o] = bias[o];
  for (int k = 0; k < K; k += 4) {
    float4 xv = *reinterpret_cast<const float4*>(xr + k);
#pragma unroll
    for (int o = 0; o < 64; ++o) {
      float4 wv = *reinterpret_cast<const float4*>(&ws[o * K + k]);
      acc[o] = fmaf(xv.x, wv.x, acc[o]);
      acc[o] = fmaf(xv.y, wv.y, acc[o]);
      acc[o] = fmaf(xv.z, wv.z, acc[o]);
      acc[o] = fmaf(xv.w, wv.w, acc[o]);
    }
  }
  float cf = (float)cnt[node];
  float inv = cf > 0.f ? 1.f / cf : 0.f;
  const float* ar = agg + (size_t)node * 64;
  float4* hr = reinterpret_cast<float4*>(hout + (size_t)node * 64);
#pragma unroll
  for (int o4 = 0; o4 < 16; ++o4) {
    float4 a = reinterpret_cast<const float4*>(ar)[o4];
    float4 v;
    v.x = fmaf(a.x, inv, acc[4 * o4 + 0]); v.x = v.x > 0.f ? v.x : 0.f;
    v.y = fmaf(a.y, inv, acc[4 * o4 + 1]); v.y = v.y > 0.f ? v.y : 0.f;
    v.z = fmaf(a.z, inv, acc[4 * o4 + 2]); v.z = v.z > 0.f ? v.z : 0.f;
    v.w = fmaf(a.w, inv, acc[4 * o4 + 3]); v.w = v.w > 0.f ? v.w : 0.f;
    hr[o4] = v;
  }
}

// global mean pool, two-stage: grid-stride (wave per node, lane=feature) ->
// LDS sacc[8][64] via ds_add_f32 (conflict-free, <=4-way same-addr) ->
// one global atomicAdd per (g,feat) per block.
__global__ void k_gmp(const float* __restrict__ h, const int* __restrict__ batch,
                      const int* __restrict__ gP, float* __restrict__ xs_sum,
                      float* __restrict__ gcnt, int count_nodes, int n) {
  __shared__ float sacc[8 * 64];
  __shared__ float scnt[8];
  int G = *gP;
  for (int i = threadIdx.x; i < 8 * 64; i += blockDim.x) sacc[i] = 0.f;
  if (threadIdx.x < 8) scnt[threadIdx.x] = 0.f;
  __syncthreads();
  int lane = threadIdx.x & 63, w = threadIdx.x >> 6;
  int stride = gridDim.x * 4;
  for (int node = blockIdx.x * 4 + w; node < n; node += stride) {
    int g = batch[node];
    if (g < 0 || g >= G || g >= 8) continue;
    float v = h[(size_t)node * 64 + lane];
    atomicAdd(&sacc[g * 64 + lane], v);
    if (count_nodes && lane == 0) atomicAdd(&scnt[g], 1.f);
  }
  __syncthreads();
  int lim = (G < 8 ? G : 8) * 64;
  for (int i = threadIdx.x; i < lim; i += blockDim.x) {
    float s = sacc[i];
    if (s != 0.f) atomicAdd(&xs_sum[i], s);
  }
  if (count_nodes && threadIdx.x < 8) {
    float c = scnt[threadIdx.x];
    if (c != 0.f) atomicAdd(&gcnt[threadIdx.x], c);
  }
}

// raw edge score: dot(concat(h[s],h[d]), pool_w) + pool_b   (wave per edge)
__global__ void k_raw(const float* __restrict__ h, const int* __restrict__ src,
                      const int* __restrict__ dst, const float* __restrict__ pw,
                      const float* __restrict__ pbp, float* __restrict__ raw, int e) {
  int idx = blockIdx.x * blockDim.x + threadIdx.x;
  int edge = idx >> 6, lane = idx & 63;
  if (edge >= e) return;
  int s = src[edge], d = dst[edge];
  float v = h[(size_t)s * 64 + lane] * pw[lane] + h[(size_t)d * 64 + lane] * pw[64 + lane];
#pragma unroll
  for (int off = 32; off > 0; off >>= 1) v += __shfl_down(v, off, 64);
  if (lane == 0) raw[edge] = v + pbp[0];
}

__global__ void k_max(const float* __restrict__ raw, const int* __restrict__ dst,
                      u32* __restrict__ m_enc, int e) {
  int i = blockIdx.x * blockDim.x + threadIdx.x;
  if (i < e) atomicMax(&m_enc[dst[i]], enc_f32(raw[i]));
}

__global__ void k_den(const float* __restrict__ raw, const int* __restrict__ dst,
                      const u32* __restrict__ m_enc, float* __restrict__ den, int e) {
  int i = blockIdx.x * blockDim.x + threadIdx.x;
  if (i >= e) return;
  int d = dst[i];
  atomicAdd(&den[d], expf(raw[i] - dec_f32(m_enc[d])));
}

// score (in place over raw), sort key, initial edge list, counters
__global__ void k_score(float* __restrict__ rawsc, const int* __restrict__ dst,
                        const u32* __restrict__ m_enc, const float* __restrict__ den,
                        u64* __restrict__ key, int* __restrict__ listA,
                        int* __restrict__ c0, int e) {
  int i = blockIdx.x * blockDim.x + threadIdx.x;
  if (i == 0) *c0 = e;  // n_in for round 0 (c1, nclus already zeroed)
  if (i >= e) return;
  int d = dst[i];
  float sc = expf(rawsc[i] - dec_f32(m_enc[d])) / den[d] + 0.5f;
  rawsc[i] = sc;
  key[i] = ((u64)(~__float_as_uint(sc)) << 32) | (u32)i;  // score desc, idx asc
  listA[i] = i;
}

// matching round, phase 1: drop dead edges, atomicMin priorities, compact
__global__ void k_mscan(const u64* __restrict__ key, const int* __restrict__ src,
                        const int* __restrict__ dst, const u8* __restrict__ dead,
                        u64* __restrict__ bcur, u64* __restrict__ bnext,
                        const int* __restrict__ list_in, int* __restrict__ list_out,
                        const int* __restrict__ n_in_p, int* __restrict__ n_out_p) {
  int n_in = *n_in_p;
  int stride = gridDim.x * blockDim.x;
  for (int i = blockIdx.x * blockDim.x + threadIdx.x; i < n_in; i += stride) {
    int e = list_in[i];
    int s = src[e], d = dst[e];
    if (dead[s] || dead[d]) continue;
    u64 k = key[e];
    atomicMin(&bcur[s], k);
    if (d != s) atomicMin(&bcur[d], k);
    bnext[s] = ~0ull;  // pre-reset other buffer for next round (benign races)
    bnext[d] = ~0ull;
    int j = atomicAdd(n_out_p, 1);  // compiler wave-aggregates +1 atomics (m20)
    list_out[j] = e;
  }
}

// matching round, phase 2: locally-dominant edges match; zero next counter
__global__ void k_mmatch(const u64* __restrict__ key, const int* __restrict__ src,
                         const int* __restrict__ dst, u8* __restrict__ dead,
                         u8* __restrict__ matched, const u64* __restrict__ bcur,
                         const int* __restrict__ list, const int* __restrict__ n_p,
                         int* __restrict__ zero_me) {
  if (blockIdx.x == 0 && threadIdx.x == 0) *zero_me = 0;
  int n = *n_p;
  int stride = gridDim.x * blockDim.x;
  for (int i = blockIdx.x * blockDim.x + threadIdx.x; i < n; i += stride) {
    int e = list[i];
    int s = src[e], d = dst[e];
    u64 k = key[e];
    if (bcur[s] == k && (d == s || bcur[d] == k)) {
      matched[e] = 1;
      dead[s] = 1;
      dead[d] = 1;
    }
  }
}

// exact sequential tail: repeatedly match the min-key alive edge
__global__ void k_tail(const u64* __restrict__ key, const int* __restrict__ src,
                       const int* __restrict__ dst, u8* dead, u8* matched,
                       const int* __restrict__ list, const int* __restrict__ n_p) {
  __shared__ u64 smk[256];
  __shared__ int sme[256];
  int n = *n_p;
  int tid = threadIdx.x;
  while (true) {
    u64 mk = ~0ull;
    int me = -1;
    for (int i = tid; i < n; i += 256) {
      int e = list[i];
      if (dead[src[e]] || dead[dst[e]]) continue;
      u64 k = key[e];
      if (k < mk) { mk = k; me = e; }
    }
    smk[tid] = mk; sme[tid] = me;
    __syncthreads();
    for (int w = 128; w > 0; w >>= 1) {
      if (tid < w && smk[tid + w] < smk[tid]) { smk[tid] = smk[tid + w]; sme[tid] = sme[tid + w]; }
      __syncthreads();
    }
    if (smk[0] == ~0ull) break;
    if (tid == 0) {
      int e = sme[0];
      matched[e] = 1;
      dead[src[e]] = 1;
      dead[dst[e]] = 1;
      __threadfence_block();
    }
    __syncthreads();
  }
}

__global__ void k_clinit(int* __restrict__ new_batch, const int* __restrict__ gP, int n) {
  int i = blockIdx.x * blockDim.x + threadIdx.x;
  if (i < n) new_batch[i] = *gP;
}

__global__ void k_build_m(const u8* __restrict__ matched, const int* __restrict__ src,
                          const int* __restrict__ dst, const int* __restrict__ batch,
                          int* __restrict__ cluster, int* __restrict__ new_batch,
                          int* __restrict__ nclus, float* __restrict__ gccnt, int e) {
  __shared__ int sc[8];
  if (threadIdx.x < 8) sc[threadIdx.x] = 0;
  __syncthreads();
  int i = blockIdx.x * blockDim.x + threadIdx.x;
  if (i < e && matched[i]) {
    int c = atomicAdd(nclus, 1);
    int s = src[i], d = dst[i];
    cluster[s] = c;
    cluster[d] = c;
    int g = batch[s];
    new_batch[c] = g;
    if (g >= 0 && g < 8) atomicAdd(&sc[g], 1);
  }
  __syncthreads();
  if (threadIdx.x < 8 && sc[threadIdx.x] > 0)
    atomicAdd(&gccnt[threadIdx.x], (float)sc[threadIdx.x]);
}

__global__ void k_build_s(const u8* __restrict__ dead, const int* __restrict__ batch,
                          int* __restrict__ cluster, int* __restrict__ new_batch,
                          int* __restrict__ nclus, float* __restrict__ gccnt, int n) {
  __shared__ int sc[8];
  if (threadIdx.x < 8) sc[threadIdx.x] = 0;
  __syncthreads();
  int i = blockIdx.x * blockDim.x + threadIdx.x;
  if (i < n && !dead[i]) {
    int c = atomicAdd(nclus, 1);
    cluster[i] = c;
    int g = batch[i];
    new_batch[c] = g;
    if (g >= 0 && g < 8) atomicAdd(&sc[g], 1);
  }
  __syncthreads();
  if (threadIdx.x < 8 && sc[threadIdx.x] > 0)
    atomicAdd(&gccnt[threadIdx.x], (float)sc[threadIdx.x]);
}

// new_x rows: matched pairs (scaled by score) and singletons. wave per item.
__global__ void k_newx(const u8* __restrict__ matched, const u8* __restrict__ dead,
                       const int* __restrict__ src, const int* __restrict__ dst,
                       const int* __restrict__ cluster, const float* __restrict__ score,
                       const float* __restrict__ h2, float* __restrict__ new_x,
                       int e, int n) {
  int idx = blockIdx.x * blockDim.x + threadIdx.x;
  int item = idx >> 6, lane = idx & 63;
  if (item < e) {
    if (!matched[item]) return;
    int s = src[item], d = dst[item];
    int c = cluster[s];
    float v = h2[(size_t)s * 64 + lane];
    if (d != s) v += h2[(size_t)d * 64 + lane];
    new_x[(size_t)c * 64 + lane] = v * score[item];
  } else if (item < e + n) {
    int node = item - e;
    if (dead[node]) return;
    new_x[(size_t)cluster[node] * 64 + lane] = h2[(size_t)node * 64 + lane];
  }
}

#define HBITS 21
#define HMASK ((1u << HBITS) - 1u)

// coalesce(cluster[edge_index]): hash-dedup; dups -> sentinel n. counts kept.
__global__ void k_dedup(const int* __restrict__ src, const int* __restrict__ dst,
                        const int* __restrict__ cluster, u64* __restrict__ table,
                        int* __restrict__ ns, int* __restrict__ nd,
                        int* __restrict__ cnt, int e, int n) {
  int i = blockIdx.x * blockDim.x + threadIdx.x;
  if (i >= e) return;
  int cs_ = cluster[src[i]], cd_ = cluster[dst[i]];
  u64 kk = (u64)cs_ * (u64)(n + 1) + (u64)cd_;
  u32 pos = (u32)((kk * 0x9E3779B97F4A7C15ull) >> 43) & HMASK;
  while (true) {
    u64 old = atomicCAS(&table[pos], ~0ull, kk);
    if (old == ~0ull) {
      ns[i] = cs_; nd[i] = cd_;
      atomicAdd(&cnt[cd_], 1);
      return;
    }
    if (old == kk) { ns[i] = n; nd[i] = n; return; }
    pos = (pos + 1) & HMASK;
  }
}

// JumpingKnowledge cat + lin1 + relu + lin2 + log_softmax. single block.
__global__ void k_head(const float* __restrict__ xs_sum /*4*8*64*/,
                       const float* __restrict__ gncnt, const float* __restrict__ gccnt,
                       const float* __restrict__ l1w, const float* __restrict__ l1b,
                       const float* __restrict__ l2w, const float* __restrict__ l2b,
                       const int* __restrict__ gP, float* __restrict__ out, int C) {
  __shared__ float z[8][256];
  __shared__ float z1[8][64];
  __shared__ float z2[8][16];
  int G = *gP;
  int tid = threadIdx.x;
  int p = tid >> 6, f = tid & 63;
  for (int g = 0; g < G; ++g) {
    float c = (p < 2) ? gncnt[g] : gccnt[g];
    if (c < 1.f) c = 1.f;
    z[g][tid] = xs_sum[(p * 8 + g) * 64 + f] / c;
  }
  __syncthreads();
  for (int idx = tid; idx < G * 64; idx += blockDim.x) {
    int g = idx >> 6, o = idx & 63;
    float a = l1b[o];
    for (int k = 0; k < 256; ++k) a = fmaf(z[g][k], l1w[o * 256 + k], a);
    z1[g][o] = a > 0.f ? a : 0.f;
  }
  __syncthreads();
  for (int idx = tid; idx < G * C; idx += blockDim.x) {
    int g = idx / C, c = idx % C;
    float a = l2b[c];
    for (int k = 0; k < 64; ++k) a = fmaf(z1[g][k], l2w[c * 64 + k], a);
    z2[g][c] = a;
  }
  __syncthreads();
  if (tid < G) {
    float m = z2[tid][0];
    for (int c = 1; c < C; ++c) m = fmaxf(m, z2[tid][c]);
    float s = 0.f;
    for (int c = 0; c < C; ++c) s += expf(z2[tid][c] - m);
    float lse = m + logf(s);
    for (int c = 0; c < C; ++c) out[tid * C + c] = z2[tid][c] - lse;
  }
}

extern "C" void kernel_launch(void* const* d_in, const int* in_sizes, int n_in,
                              void* d_out, int out_size, void* d_ws, size_t ws_size,
                              hipStream_t stream) {
  const float* x       = (const float*)d_in[0];
  const int*   ei      = (const int*)d_in[1];
  const int*   batch   = (const int*)d_in[2];
  const float* w_rel1  = (const float*)d_in[3];
  const float* b_rel1  = (const float*)d_in[4];
  const float* w_root1 = (const float*)d_in[5];
  const float* w_rel2  = (const float*)d_in[6];
  const float* b_rel2  = (const float*)d_in[7];
  const float* w_root2 = (const float*)d_in[8];
  const float* w_rel3  = (const float*)d_in[9];
  const float* b_rel3  = (const float*)d_in[10];
  const float* w_root3 = (const float*)d_in[11];
  const float* w_rel4  = (const float*)d_in[12];
  const float* b_rel4  = (const float*)d_in[13];
  const float* w_root4 = (const float*)d_in[14];
  const float* pool_w  = (const float*)d_in[15];
  const float* pool_b  = (const float*)d_in[16];
  const float* lin1_w  = (const float*)d_in[17];
  const float* lin1_b  = (const float*)d_in[18];
  const float* lin2_w  = (const float*)d_in[19];
  const float* lin2_b  = (const float*)d_in[20];
  const int*   gP      = (const int*)d_in[21];
  float* out = (float*)d_out;

  const int N = in_sizes[2];
  const int E = in_sizes[1] / 2;
  const int C = in_sizes[20];
  const int* src = ei;
  const int* dst = ei + E;

  // ---- workspace layout ----
  char* w = (char*)d_ws;
  auto alloc = [&](size_t bytes) -> char* {
    char* p = w;
    w += (bytes + 255) & ~(size_t)255;
    return p;
  };
  float* r      = (float*)alloc((size_t)N * 64 * 4);
  float* agg    = (float*)alloc((size_t)(N + 1) * 64 * 4);  // also hash table region
  float* hA     = (float*)alloc((size_t)N * 64 * 4);        // h1 -> new_x -> h4
  float* hB     = (float*)alloc((size_t)N * 64 * 4);        // h2 -> h3
  float* score  = (float*)alloc((size_t)E * 4);             // raw -> score
  u64*   key    = (u64*)alloc((size_t)E * 8);
  int*   listA  = (int*)alloc((size_t)E * 4);               // later: ns
  int*   listB  = (int*)alloc((size_t)E * 4);               // later: nd
  u64*   best0  = (u64*)alloc((size_t)N * 8);
  u64*   best1  = (u64*)alloc((size_t)N * 8);
  char* zstart = w;                                         // zeroed block
  int*   cnt       = (int*)alloc((size_t)(N + 1) * 4);
  u32*   m_enc     = (u32*)alloc((size_t)N * 4);
  float* den       = (float*)alloc((size_t)N * 4);
  u8*    dead      = (u8*)alloc((size_t)N);
  u8*    matched   = (u8*)alloc((size_t)E);
  int*   cluster   = (int*)alloc((size_t)N * 4);
  int*   new_batch = (int*)alloc((size_t)N * 4);
  float* small     = (float*)alloc(16384);
  size_t zbytes = (size_t)(w - zstart);
  if ((size_t)(w - (char*)d_ws) > ws_size) return;  // fail loudly (output stays poisoned)

  float* xs_sum = small;               // [4][8][64]
  float* gncnt  = small + 2048;        // [8] node counts / graph
  float* gccnt  = small + 2056;        // [8] cluster counts / graph
  int*   cptr   = (int*)(small + 2064);  // c0, c1 (ping-pong list counters)
  int*   nclusP = (int*)(small + 2066);

  const int TB = 256;
  const int gN = (N + TB - 1) / TB;
  const int gE = (E + TB - 1) / TB;
  const int gEw = (int)(((size_t)E * 64 + TB - 1) / TB);
  const int gENw = (int)(((size_t)(E + N) * 64 + TB - 1) / TB);
  const int gGmp = 1024;  // grid-stride two-stage reduction
  const size_t aggBytes = (size_t)(N + 1) * 64 * 4;

  hipMemsetAsync(zstart, 0, zbytes, stream);
  hipMemsetAsync(best0, 0xFF, (size_t)N * 8, stream);
  hipMemsetAsync(best1, 0xFF, (size_t)N * 8, stream);
  hipMemsetAsync(agg, 0, aggBytes, stream);

  // ---- conv1 (F=128 -> 64) + gmp xs0 ----
  k_transform<128><<<gN, TB, 0, stream>>>(x, w_rel1, r, N);
  k_count<<<gE, TB, 0, stream>>>(dst, cnt, E);
  k_aggregate<<<gEw, TB, 0, stream>>>(r, src, dst, agg, E, N);
  k_finish<128><<<gN, TB, 0, stream>>>(x, agg, cnt, w_root1, b_rel1, hA, N);
  k_gmp<<<gGmp, TB, 0, stream>>>(hA, batch, gP, xs_sum + 0 * 512, gncnt, 1, N);

  // ---- conv2 (64 -> 64) + gmp xs1 ----
  hipMemsetAsync(agg, 0, aggBytes, stream);
  k_transform<64><<<gN, TB, 0, stream>>>(hA, w_rel2, r, N);
  k_aggregate<<<gEw, TB, 0, stream>>>(r, src, dst, agg, E, N);
  k_finish<64><<<gN, TB, 0, stream>>>(hA, agg, cnt, w_root2, b_rel2, hB, N);
  k_gmp<<<gGmp, TB, 0, stream>>>(hB, batch, gP, xs_sum + 1 * 512, nullptr, 0, N);

  // ---- edge pooling: scores ----
  k_raw<<<gEw, TB, 0, stream>>>(hB, src, dst, pool_w, pool_b, score, E);
  k_max<<<gE, TB, 0, stream>>>(score, dst, m_enc, E);
  k_den<<<gE, TB, 0, stream>>>(score, dst, m_enc, den, E);
  k_score<<<gE, TB, 0, stream>>>(score, dst, m_enc, den, key, listA, cptr, E);

  // ---- greedy matching: locally-dominant rounds + exact tail ----
  const int R = 32;
  for (int rr = 0; rr < R; ++rr) {
    u64* bcur = (rr & 1) ? best1 : best0;
    u64* bnext = (rr & 1) ? best0 : best1;
    int* lin = (rr & 1) ? listB : listA;
    int* lout = (rr & 1) ? listA : listB;
    int* cin = cptr + (rr & 1);
    int* cout = cptr + ((rr + 1) & 1);
    k_mscan<<<1024, TB, 0, stream>>>(key, src, dst, dead, bcur, bnext, lin, lout, cin, cout);
    k_mmatch<<<1024, TB, 0, stream>>>(key, src, dst, dead, matched, bcur, lout, cout, cin);
  }
  k_tail<<<1, TB, 0, stream>>>(key, src, dst, dead, matched,
                               (R & 1) ? listB : listA, cptr + (R & 1));

  // ---- clusters, new_x, new_batch ----
  k_clinit<<<gN, TB, 0, stream>>>(new_batch, gP, N);
  k_build_m<<<gE, TB, 0, stream>>>(matched, src, dst, batch, cluster, new_batch, nclusP, gccnt, E);
  k_build_s<<<gN, TB, 0, stream>>>(dead, batch, cluster, new_batch, nclusP, gccnt, N);
  hipMemsetAsync(hA, 0, (size_t)N * 64 * 4, stream);  // hA becomes new_x
  k_newx<<<gENw, TB, 0, stream>>>(matched, dead, src, dst, cluster, score, hB, hA, E, N);

  // ---- coalesce edges (hash in agg region) ----
  hipMemsetAsync(agg, 0xFF, ((size_t)1 << HBITS) * 8, stream);
  hipMemsetAsync(cnt, 0, (size_t)(N + 1) * 4, stream);
  k_dedup<<<gE, TB, 0, stream>>>(src, dst, cluster, (u64*)agg, listA, listB, cnt, E, N);

  // ---- conv3 (64 -> 64) + gmp xs2 ----
  hipMemsetAsync(agg, 0, aggBytes, stream);
  k_transform<64><<<gN, TB, 0, stream>>>(hA, w_rel3, r, N);
  k_aggregate<<<gEw, TB, 0, stream>>>(r, listA, listB, agg, E, N);
  k_finish<64><<<gN, TB, 0, stream>>>(hA, agg, cnt, w_root3, b_rel3, hB, N);
  k_gmp<<<gGmp, TB, 0, stream>>>(hB, new_batch, gP, xs_sum + 2 * 512, nullptr, 0, N);

  // ---- conv4 (64 -> 64) + gmp xs3 ----
  hipMemsetAsync(agg, 0, aggBytes, stream);
  k_transform<64><<<gN, TB, 0, stream>>>(hB, w_rel4, r, N);
  k_aggregate<<<gEw, TB, 0, stream>>>(r, listA, listB, agg, E, N);
  k_finish<64><<<gN, TB, 0, stream>>>(hB, agg, cnt, w_root4, b_rel4, hA, N);
  k_gmp<<<gGmp, TB, 0, stream>>>(hA, new_batch, gP, xs_sum + 3 * 512, nullptr, 0, N);

  // ---- head ----
  k_head<<<1, TB, 0, stream>>>(xs_sum, gncnt, gccnt, lin1_w, lin1_b, lin2_w, lin2_b, gP, out, C);
}